// Round 3
// baseline (2435.854 us; speedup 1.0000x reference)
//
#include <hip/hip_runtime.h>
#include <math.h>

#define N_ATOMS 50000
#define D 32
#define E_EDGES 300000
#define BD 16
#define NCH 17              // BD + 1 bias channel
#define QW (NCH * D)        // 544
#define TILE 16
#define NTILES (N_ATOMS / TILE)               // 3125 exact
#define SCAN_BLOCKS ((N_ATOMS + 255) / 256)   // 196

__device__ __forceinline__ float sigmoidf_(float x) {
    return 1.0f / (1.0f + __expf(-x));
}
__device__ __forceinline__ float dot4_(float4 a, float4 b, float acc) {
    return fmaf(a.x, b.x, fmaf(a.y, b.y, fmaf(a.z, b.z, fmaf(a.w, b.w, acc))));
}

// ---------- precompute kernels (once per launch) ----------

// WT2[i][s], i-major, s = b*32 + j ; channel b=16 is Bm (bias.reshape(D,D))
__global__ void k_build_wt(const float* __restrict__ kern,
                           const float* __restrict__ bias,
                           float* __restrict__ WT2) {
    int idx = blockIdx.x * 256 + threadIdx.x;
    if (idx >= D * QW) return;
    int i = idx / QW;
    int s = idx - i * QW;
    int b = s >> 5, j = s & 31;
    WT2[idx] = (b < BD) ? kern[b * (D * D) + i * D + j] : bias[i * D + j];
}

__global__ void k_hist(const int* __restrict__ pair, int* __restrict__ deg) {
    int e = blockIdx.x * 256 + threadIdx.x;
    if (e < E_EDGES) atomicAdd(&deg[pair[2 * e]], 1);
}

__global__ void k_scan1(const int* __restrict__ deg, int* __restrict__ offs,
                        int* __restrict__ bsums) {
    __shared__ int sm[256];
    int t = threadIdx.x, gid = blockIdx.x * 256 + t;
    int v = (gid < N_ATOMS) ? deg[gid] : 0;
    sm[t] = v;
    __syncthreads();
    for (int off = 1; off < 256; off <<= 1) {
        int x = (t >= off) ? sm[t - off] : 0;
        __syncthreads();
        sm[t] += x;
        __syncthreads();
    }
    if (gid < N_ATOMS) offs[gid] = sm[t] - v;
    if (t == 255) bsums[blockIdx.x] = sm[255];
}

__global__ void k_scan2(const int* __restrict__ bsums, int* __restrict__ boffs, int nb) {
    __shared__ int sm[256];
    int t = threadIdx.x;
    int v = (t < nb) ? bsums[t] : 0;
    sm[t] = v;
    __syncthreads();
    for (int off = 1; off < 256; off <<= 1) {
        int x = (t >= off) ? sm[t - off] : 0;
        __syncthreads();
        sm[t] += x;
        __syncthreads();
    }
    if (t < nb) boffs[t] = sm[t] - v;
}

__global__ void k_scan3(int* __restrict__ offs, const int* __restrict__ boffs) {
    int gid = blockIdx.x * 256 + threadIdx.x;
    if (gid < N_ATOMS) offs[gid] += boffs[blockIdx.x];
}

// sedge.x = src | (r_local << 20), sedge.y = eid   (src < 2^17, r_local < 16)
__global__ void k_scatter(const int* __restrict__ pair, const int* __restrict__ offs,
                          int* __restrict__ cursor, int2* __restrict__ sedge) {
    int e = blockIdx.x * 256 + threadIdx.x;
    if (e >= E_EDGES) return;
    int d = pair[2 * e], s = pair[2 * e + 1];
    int pos = offs[d] + atomicAdd(&cursor[d], 1);
    sedge[pos] = make_int2(s | ((d & (TILE - 1)) << 20), e);
}

// ---------- fused per-step kernel ----------
__global__ __launch_bounds__(256, 4)
void k_step(const float* __restrict__ h_in, float* __restrict__ h_out,
            const float* __restrict__ bond, const float* __restrict__ WT2,
            const int* __restrict__ offs, const int* __restrict__ deg,
            const int2* __restrict__ sedge,
            const float* __restrict__ Wih, const float* __restrict__ Whh,
            const float* __restrict__ bih, const float* __restrict__ bhh) {
    __shared__ float q_lds[TILE][QW];     // 34816 B, bank(s) = s&31 = j
    __shared__ float agg_lds[TILE][36];   // 2304 B
    __shared__ float h_tile[TILE][36];    // 2304 B

    const int t = threadIdx.x;
    const int base = blockIdx.x * TILE;
    const int half = t >> 5;   // 0..7
    const int j = t & 31;

    // ---- prologue: zero q_lds/agg_lds, load h_tile (coalesced)
#pragma unroll
    for (int k = 0; k < (TILE * QW) / 256; ++k)
        ((float*)q_lds)[t + 256 * k] = 0.f;
    {
        const int r = t >> 5;
        h_tile[r][j]     = h_in[base * D + t];
        h_tile[r + 8][j] = h_in[base * D + 256 + t];
        agg_lds[r][j]     = 0.f;
        agg_lds[r + 8][j] = 0.f;
    }
    __syncthreads();

    // ---- phase 1: edge-parallel q accumulation (8 half-wave chunks)
    {
        const int estart = offs[base];
        const int last = base + TILE - 1;
        const int eend = offs[last] + deg[last];
        const int ecnt = eend - estart;
        const int cs = (ecnt + 7) >> 3;
        int p = estart + half * cs;
        const int pe = min(p + cs, eend);

        float q[NCH];
#pragma unroll
        for (int k = 0; k < NCH; ++k) q[k] = 0.f;
        int rcur = -1;

        for (; p < pe; ++p) {
            const int2 ed = sedge[p];
            const int r = ed.x >> 20;
            const int src = ed.x & 0xFFFFF;
            if (r != rcur) {
                if (rcur >= 0) {
#pragma unroll
                    for (int k = 0; k < NCH; ++k)
                        atomicAdd(&q_lds[rcur][k * 32 + j], q[k]);
#pragma unroll
                    for (int k = 0; k < NCH; ++k) q[k] = 0.f;
                }
                rcur = r;
            }
            const float hj = h_in[src * D + j];
            const float4* bp = (const float4*)(bond + (size_t)ed.y * BD);
            float4 b;
            b = bp[0];
            q[0] = fmaf(b.x, hj, q[0]);
            q[1] = fmaf(b.y, hj, q[1]);
            q[2] = fmaf(b.z, hj, q[2]);
            q[3] = fmaf(b.w, hj, q[3]);
            b = bp[1];
            q[4] = fmaf(b.x, hj, q[4]);
            q[5] = fmaf(b.y, hj, q[5]);
            q[6] = fmaf(b.z, hj, q[6]);
            q[7] = fmaf(b.w, hj, q[7]);
            b = bp[2];
            q[8]  = fmaf(b.x, hj, q[8]);
            q[9]  = fmaf(b.y, hj, q[9]);
            q[10] = fmaf(b.z, hj, q[10]);
            q[11] = fmaf(b.w, hj, q[11]);
            b = bp[3];
            q[12] = fmaf(b.x, hj, q[12]);
            q[13] = fmaf(b.y, hj, q[13]);
            q[14] = fmaf(b.z, hj, q[14]);
            q[15] = fmaf(b.w, hj, q[15]);
            q[16] += hj;
        }
        if (rcur >= 0) {
#pragma unroll
            for (int k = 0; k < NCH; ++k)
                atomicAdd(&q_lds[rcur][k * 32 + j], q[k]);
        }
    }
    __syncthreads();

    // ---- phase 2: agg[r][j] += sum_{s in my 68-chunk} WT2[j][s] * q[r][s]
    //      two passes of 8 rows to keep the accumulator array small (no spill)
    {
        const int s0 = half * (QW / 8);   // 68-wide chunk, 16B-aligned
        const float4* wrow = (const float4*)(WT2 + (size_t)j * QW + s0);
#pragma unroll
        for (int pass = 0; pass < 2; ++pass) {
            const int rb = ((pass ^ (half & 1)) & 1) * 8;  // halves alternate row-sets
            float acc[8];
#pragma unroll
            for (int r = 0; r < 8; ++r) acc[r] = 0.f;
            for (int sq = 0; sq < (QW / 8) / 4; ++sq) {    // 17 iters
                const float4 wv = wrow[sq];
#pragma unroll
                for (int r = 0; r < 8; ++r) {
                    const float4 qv = *(const float4*)&q_lds[rb + r][s0 + sq * 4];
                    acc[r] = dot4_(wv, qv, acc[r]);
                }
            }
#pragma unroll
            for (int r = 0; r < 8; ++r)
                atomicAdd(&agg_lds[rb + r][j], acc[r]);
        }
    }
    __syncthreads();

    // ---- phase 3: GRU cell (2 items/thread: (r,i) = item>>5, item&31)
#pragma unroll
    for (int it = 0; it < 2; ++it) {
        const int item = t + it * 256;
        const int r = item >> 5;
        const int i = item & 31;
        float gri = bih[i], gzi = bih[32 + i], gni = bih[64 + i];
        float grh = bhh[i], gzh = bhh[32 + i], gnh = bhh[64 + i];
        const float4* w0 = (const float4*)(Wih + (size_t)i * D);
        const float4* w1 = (const float4*)(Wih + (size_t)(32 + i) * D);
        const float4* w2 = (const float4*)(Wih + (size_t)(64 + i) * D);
        const float4* u0 = (const float4*)(Whh + (size_t)i * D);
        const float4* u1 = (const float4*)(Whh + (size_t)(32 + i) * D);
        const float4* u2 = (const float4*)(Whh + (size_t)(64 + i) * D);
#pragma unroll
        for (int jq = 0; jq < 8; ++jq) {
            const float4 xv = *(const float4*)&agg_lds[r][jq * 4];
            const float4 hv = *(const float4*)&h_tile[r][jq * 4];
            gri = dot4_(w0[jq], xv, gri);
            gzi = dot4_(w1[jq], xv, gzi);
            gni = dot4_(w2[jq], xv, gni);
            grh = dot4_(u0[jq], hv, grh);
            gzh = dot4_(u1[jq], hv, gzh);
            gnh = dot4_(u2[jq], hv, gnh);
        }
        const float rg = sigmoidf_(gri + grh);
        const float zg = sigmoidf_(gzi + gzh);
        float xn = gni + rg * gnh;
        xn = fminf(fmaxf(xn, -15.f), 15.f);
        const float e2 = __expf(2.f * xn);
        const float ng = (e2 - 1.f) / (e2 + 1.f);
        h_out[base * D + item] = (1.f - zg) * ng + zg * h_tile[r][i];
    }
}

// ---------- launch ----------
extern "C" void kernel_launch(void* const* d_in, const int* in_sizes, int n_in,
                              void* d_out, int out_size, void* d_ws, size_t ws_size,
                              hipStream_t stream) {
    const float* atom = (const float*)d_in[0];
    const float* bond = (const float*)d_in[1];
    const int*   pair = (const int*)d_in[2];
    const float* kern = (const float*)d_in[3];
    const float* bias = (const float*)d_in[4];
    const float* Wih  = (const float*)d_in[5];
    const float* Whh  = (const float*)d_in[6];
    const float* bih  = (const float*)d_in[7];
    const float* bhh  = (const float*)d_in[8];
    float* out = (float*)d_out;

    char* w = (char*)d_ws;
    auto alloc = [&](size_t bytes) {
        char* p = w;
        w += (bytes + 255) & ~size_t(255);
        return p;
    };
    float* hA     = (float*)alloc((size_t)N_ATOMS * D * 4);
    float* WT2    = (float*)alloc((size_t)D * QW * 4);
    int*   deg    = (int*)alloc((size_t)N_ATOMS * 4);
    int*   offs   = (int*)alloc((size_t)N_ATOMS * 4);
    int*   cursor = (int*)alloc((size_t)N_ATOMS * 4);
    int*   bsums  = (int*)alloc(256 * 4);
    int*   boffs  = (int*)alloc(256 * 4);
    int2*  sedge  = (int2*)alloc((size_t)E_EDGES * 8);

    hipMemsetAsync(deg, 0, (size_t)N_ATOMS * 4, stream);
    hipMemsetAsync(cursor, 0, (size_t)N_ATOMS * 4, stream);

    k_build_wt<<<(D * QW + 255) / 256, 256, 0, stream>>>(kern, bias, WT2);
    k_hist<<<(E_EDGES + 255) / 256, 256, 0, stream>>>(pair, deg);
    k_scan1<<<SCAN_BLOCKS, 256, 0, stream>>>(deg, offs, bsums);
    k_scan2<<<1, 256, 0, stream>>>(bsums, boffs, SCAN_BLOCKS);
    k_scan3<<<SCAN_BLOCKS, 256, 0, stream>>>(offs, boffs);
    k_scatter<<<(E_EDGES + 255) / 256, 256, 0, stream>>>(pair, offs, cursor, sedge);

    // 4 message-passing + GRU steps, ping-pong h between hA and d_out
    k_step<<<NTILES, 256, 0, stream>>>(atom, hA, bond, WT2, offs, deg, sedge,
                                       Wih, Whh, bih, bhh);
    k_step<<<NTILES, 256, 0, stream>>>(hA, out, bond, WT2, offs, deg, sedge,
                                       Wih, Whh, bih, bhh);
    k_step<<<NTILES, 256, 0, stream>>>(out, hA, bond, WT2, offs, deg, sedge,
                                       Wih, Whh, bih, bhh);
    k_step<<<NTILES, 256, 0, stream>>>(hA, out, bond, WT2, offs, deg, sedge,
                                       Wih, Whh, bih, bhh);
}

// Round 4
// 1559.471 us; speedup vs baseline: 1.5620x; 1.5620x over previous
//
#include <hip/hip_runtime.h>
#include <math.h>

#define N_ATOMS 50000
#define D 32
#define E_EDGES 300000
#define BD 16
#define NCH 17              // BD + 1 bias channel
#define QW (NCH * D)        // 544
#define TILE 16
#define NTILES (N_ATOMS / TILE)               // 3125 exact
#define SCAN_BLOCKS ((N_ATOMS + 255) / 256)   // 196
#define GRU_TILE 8
#define GRU_NT (N_ATOMS / GRU_TILE)           // 6250

__device__ __forceinline__ float sigmoidf_(float x) {
    return 1.0f / (1.0f + __expf(-x));
}
__device__ __forceinline__ float dot4_(float4 a, float4 b, float acc) {
    return fmaf(a.x, b.x, fmaf(a.y, b.y, fmaf(a.z, b.z, fmaf(a.w, b.w, acc))));
}

// ---------- precompute kernels (once per launch) ----------

// WT2[i][s], i-major, s = b*32 + j ; channel b=16 is Bm (bias.reshape(D,D))
__global__ void k_build_wt(const float* __restrict__ kern,
                           const float* __restrict__ bias,
                           float* __restrict__ WT2) {
    int idx = blockIdx.x * 256 + threadIdx.x;
    if (idx >= D * QW) return;
    int i = idx / QW;
    int s = idx - i * QW;
    int b = s >> 5, j = s & 31;
    WT2[idx] = (b < BD) ? kern[b * (D * D) + i * D + j] : bias[i * D + j];
}

__global__ void k_hist(const int* __restrict__ pair, int* __restrict__ deg) {
    int e = blockIdx.x * 256 + threadIdx.x;
    if (e < E_EDGES) atomicAdd(&deg[pair[2 * e]], 1);
}

__global__ void k_scan1(const int* __restrict__ deg, int* __restrict__ offs,
                        int* __restrict__ bsums) {
    __shared__ int sm[256];
    int t = threadIdx.x, gid = blockIdx.x * 256 + t;
    int v = (gid < N_ATOMS) ? deg[gid] : 0;
    sm[t] = v;
    __syncthreads();
    for (int off = 1; off < 256; off <<= 1) {
        int x = (t >= off) ? sm[t - off] : 0;
        __syncthreads();
        sm[t] += x;
        __syncthreads();
    }
    if (gid < N_ATOMS) offs[gid] = sm[t] - v;
    if (t == 255) bsums[blockIdx.x] = sm[255];
}

__global__ void k_scan2(const int* __restrict__ bsums, int* __restrict__ boffs, int nb) {
    __shared__ int sm[256];
    int t = threadIdx.x;
    int v = (t < nb) ? bsums[t] : 0;
    sm[t] = v;
    __syncthreads();
    for (int off = 1; off < 256; off <<= 1) {
        int x = (t >= off) ? sm[t - off] : 0;
        __syncthreads();
        sm[t] += x;
        __syncthreads();
    }
    if (t < nb) boffs[t] = sm[t] - v;
}

__global__ void k_scan3(int* __restrict__ offs, const int* __restrict__ boffs) {
    int gid = blockIdx.x * 256 + threadIdx.x;
    if (gid < N_ATOMS) offs[gid] += boffs[blockIdx.x];
}

// sedge.x = src | (r_local << 20), sedge.y = eid   (src < 2^17, r_local < 16)
__global__ void k_scatter(const int* __restrict__ pair, const int* __restrict__ offs,
                          int* __restrict__ cursor, int2* __restrict__ sedge) {
    int e = blockIdx.x * 256 + threadIdx.x;
    if (e >= E_EDGES) return;
    int d = pair[2 * e], s = pair[2 * e + 1];
    int pos = offs[d] + atomicAdd(&cursor[d], 1);
    sedge[pos] = make_int2(s | ((d & (TILE - 1)) << 20), e);
}

// ---------- message kernel: phases 1+2, writes agg to global ----------
__global__ void k_msg(const float* __restrict__ h_in, float* __restrict__ agg_g,
                      const float* __restrict__ bond, const float* __restrict__ WT2,
                      const int* __restrict__ offs, const int* __restrict__ deg,
                      const int2* __restrict__ sedge) {
    __shared__ float q_lds[TILE][QW];     // 34816 B, bank(s) = s&31
    __shared__ float agg_lds[TILE][33];   // 2112 B, stride 33 -> (r+j)%32 banks

    const int t = threadIdx.x;
    const int base = blockIdx.x * TILE;
    const int half = t >> 5;   // 0..7
    const int j = t & 31;

    // ---- prologue: zero q_lds / agg_lds
#pragma unroll
    for (int k = 0; k < (TILE * QW) / 256; ++k)
        ((float*)q_lds)[t + 256 * k] = 0.f;
    {
        const int r = t >> 5;
        agg_lds[r][j]     = 0.f;
        agg_lds[r + 8][j] = 0.f;
    }
    __syncthreads();

    // ---- phase 1: edge-parallel q accumulation (8 half-wave chunks)
    {
        const int estart = offs[base];
        const int last = base + TILE - 1;
        const int eend = offs[last] + deg[last];
        const int cs = (eend - estart + 7) >> 3;
        int p = estart + half * cs;
        const int pe = min(p + cs, eend);

        float q[NCH];
#pragma unroll
        for (int k = 0; k < NCH; ++k) q[k] = 0.f;
        int rcur = -1;

        for (; p < pe; ++p) {
            const int2 ed = sedge[p];
            const int r = ed.x >> 20;
            const int src = ed.x & 0xFFFFF;
            if (r != rcur) {
                if (rcur >= 0) {
#pragma unroll
                    for (int k = 0; k < NCH; ++k) {
                        atomicAdd(&q_lds[rcur][k * 32 + j], q[k]);
                        q[k] = 0.f;
                    }
                }
                rcur = r;
            }
            const float hj = h_in[src * D + j];
            const float4* bp = (const float4*)(bond + (size_t)ed.y * BD);
            float4 b;
            b = bp[0];
            q[0] = fmaf(b.x, hj, q[0]);
            q[1] = fmaf(b.y, hj, q[1]);
            q[2] = fmaf(b.z, hj, q[2]);
            q[3] = fmaf(b.w, hj, q[3]);
            b = bp[1];
            q[4] = fmaf(b.x, hj, q[4]);
            q[5] = fmaf(b.y, hj, q[5]);
            q[6] = fmaf(b.z, hj, q[6]);
            q[7] = fmaf(b.w, hj, q[7]);
            b = bp[2];
            q[8]  = fmaf(b.x, hj, q[8]);
            q[9]  = fmaf(b.y, hj, q[9]);
            q[10] = fmaf(b.z, hj, q[10]);
            q[11] = fmaf(b.w, hj, q[11]);
            b = bp[3];
            q[12] = fmaf(b.x, hj, q[12]);
            q[13] = fmaf(b.y, hj, q[13]);
            q[14] = fmaf(b.z, hj, q[14]);
            q[15] = fmaf(b.w, hj, q[15]);
            q[16] += hj;
        }
        if (rcur >= 0) {
#pragma unroll
            for (int k = 0; k < NCH; ++k)
                atomicAdd(&q_lds[rcur][k * 32 + j], q[k]);
        }
    }
    __syncthreads();

    // ---- phase 2: agg[r][j] += sum_{s in my 68-chunk} WT2[j][s] * q[r][s]
    {
        const int s0 = half * (QW / 8);   // 68-wide, 16B-aligned (272 B)
        const float4* wrow = (const float4*)(WT2 + (size_t)j * QW + s0);
#pragma unroll
        for (int pass = 0; pass < 2; ++pass) {
            const int rb = ((pass ^ (half & 1)) & 1) * 8;
            float acc[8];
#pragma unroll
            for (int r = 0; r < 8; ++r) acc[r] = 0.f;
            for (int sq = 0; sq < (QW / 8) / 4; ++sq) {    // 17 iters
                const float4 wv = wrow[sq];
#pragma unroll
                for (int r = 0; r < 8; ++r) {
                    const float4 qv = *(const float4*)&q_lds[rb + r][s0 + sq * 4];
                    acc[r] = dot4_(wv, qv, acc[r]);
                }
            }
#pragma unroll
            for (int r = 0; r < 8; ++r)
                atomicAdd(&agg_lds[rb + r][j], acc[r]);
        }
    }
    __syncthreads();

    // ---- epilogue: agg -> global (coalesced)
    {
        const int r = t >> 5;
        agg_g[base * D + t]       = agg_lds[r][j];
        agg_g[base * D + 256 + t] = agg_lds[r + 8][j];
    }
}

// ---------- GRU kernel: h_out = GRUCell(agg, h_in) ----------
__global__ void k_gru(const float* __restrict__ agg_g, const float* __restrict__ h_in,
                      float* __restrict__ h_out,
                      const float* __restrict__ Wih, const float* __restrict__ Whh,
                      const float* __restrict__ bih, const float* __restrict__ bhh) {
    __shared__ float Wih_s[96][33];       // 12672 B, bank (i+j)%32 -> conflict-free
    __shared__ float Whh_s[96][33];       // 12672 B
    __shared__ float bih_s[96], bhh_s[96];
    __shared__ float x_lds[GRU_TILE][32]; // broadcast reads only
    __shared__ float h_lds[GRU_TILE][32];

    const int t = threadIdx.x;

    for (int idx = t; idx < 96 * 32; idx += 256) {
        const int o = idx >> 5, j = idx & 31;
        Wih_s[o][j] = Wih[idx];
        Whh_s[o][j] = Whh[idx];
    }
    if (t < 96) { bih_s[t] = bih[t]; bhh_s[t] = bhh[t]; }
    __syncthreads();

    const int r = t >> 5;   // node within octet
    const int i = t & 31;   // output feature

    for (int tile = blockIdx.x; tile < GRU_NT; tile += gridDim.x) {
        const int base = tile * GRU_TILE;         // 8 nodes
        ((float*)x_lds)[t] = agg_g[base * D + t]; // 256 floats, coalesced
        ((float*)h_lds)[t] = h_in[base * D + t];
        __syncthreads();

        float gri = bih_s[i],      grh = bhh_s[i];
        float gzi = bih_s[32 + i], gzh = bhh_s[32 + i];
        float gni = bih_s[64 + i], gnh = bhh_s[64 + i];
#pragma unroll 8
        for (int jj = 0; jj < 32; ++jj) {
            const float xv = x_lds[r][jj];
            const float hv = h_lds[r][jj];
            gri = fmaf(Wih_s[i][jj],      xv, gri);
            gzi = fmaf(Wih_s[32 + i][jj], xv, gzi);
            gni = fmaf(Wih_s[64 + i][jj], xv, gni);
            grh = fmaf(Whh_s[i][jj],      hv, grh);
            gzh = fmaf(Whh_s[32 + i][jj], hv, gzh);
            gnh = fmaf(Whh_s[64 + i][jj], hv, gnh);
        }
        const float rg = sigmoidf_(gri + grh);
        const float zg = sigmoidf_(gzi + gzh);
        float xn = gni + rg * gnh;
        xn = fminf(fmaxf(xn, -15.f), 15.f);
        const float e2 = __expf(2.f * xn);
        const float ng = (e2 - 1.f) / (e2 + 1.f);
        h_out[base * D + t] = (1.f - zg) * ng + zg * h_lds[r][i];
        __syncthreads();   // protect x_lds/h_lds before next iteration
    }
}

// ---------- launch ----------
extern "C" void kernel_launch(void* const* d_in, const int* in_sizes, int n_in,
                              void* d_out, int out_size, void* d_ws, size_t ws_size,
                              hipStream_t stream) {
    const float* atom = (const float*)d_in[0];
    const float* bond = (const float*)d_in[1];
    const int*   pair = (const int*)d_in[2];
    const float* kern = (const float*)d_in[3];
    const float* bias = (const float*)d_in[4];
    const float* Wih  = (const float*)d_in[5];
    const float* Whh  = (const float*)d_in[6];
    const float* bih  = (const float*)d_in[7];
    const float* bhh  = (const float*)d_in[8];
    float* out = (float*)d_out;

    char* w = (char*)d_ws;
    auto alloc = [&](size_t bytes) {
        char* p = w;
        w += (bytes + 255) & ~size_t(255);
        return p;
    };
    float* hA     = (float*)alloc((size_t)N_ATOMS * D * 4);
    float* aggG   = (float*)alloc((size_t)N_ATOMS * D * 4);
    float* WT2    = (float*)alloc((size_t)D * QW * 4);
    int*   deg    = (int*)alloc((size_t)N_ATOMS * 4);
    int*   offs   = (int*)alloc((size_t)N_ATOMS * 4);
    int*   cursor = (int*)alloc((size_t)N_ATOMS * 4);
    int*   bsums  = (int*)alloc(256 * 4);
    int*   boffs  = (int*)alloc(256 * 4);
    int2*  sedge  = (int2*)alloc((size_t)E_EDGES * 8);

    hipMemsetAsync(deg, 0, (size_t)N_ATOMS * 4, stream);
    hipMemsetAsync(cursor, 0, (size_t)N_ATOMS * 4, stream);

    k_build_wt<<<(D * QW + 255) / 256, 256, 0, stream>>>(kern, bias, WT2);
    k_hist<<<(E_EDGES + 255) / 256, 256, 0, stream>>>(pair, deg);
    k_scan1<<<SCAN_BLOCKS, 256, 0, stream>>>(deg, offs, bsums);
    k_scan2<<<1, 256, 0, stream>>>(bsums, boffs, SCAN_BLOCKS);
    k_scan3<<<SCAN_BLOCKS, 256, 0, stream>>>(offs, boffs);
    k_scatter<<<(E_EDGES + 255) / 256, 256, 0, stream>>>(pair, offs, cursor, sedge);

    const float* hsrc = atom;
    float* hdst[4] = { hA, out, hA, out };
    for (int s = 0; s < 4; ++s) {
        k_msg<<<NTILES, 256, 0, stream>>>(hsrc, aggG, bond, WT2, offs, deg, sedge);
        k_gru<<<1024, 256, 0, stream>>>(aggG, hsrc, hdst[s], Wih, Whh, bih, bhh);
        hsrc = hdst[s];
    }
}